// Round 3
// baseline (620.878 us; speedup 1.0000x reference)
//
#include <hip/hip_runtime.h>

#define BATCH 131072
#define NS    300
#define H     100
#define BLK   256
#define TILE4 (BLK * NS / 4)   /* 19200 float4 outputs per block */
#define JT    25               /* j-tile: 25 accumulators, 4 tiles */

__global__ __launch_bounds__(BLK) __attribute__((amdgpu_waves_per_eu(2, 2)))
void lorentz_fused(const float* __restrict__ G,  const float* __restrict__ W1,
                   const float* __restrict__ b1, const float* __restrict__ W2,
                   const float* __restrict__ b2, const float* __restrict__ Ww0,
                   const float* __restrict__ Wwp, const float* __restrict__ Wg,
                   float* __restrict__ out)
{
    /* 100 KB LDS: phase 1 = per-thread h1 rows (thread t -> float4 slots [t*25, t*25+25)).
       phase 2 (after barrier) = sP0/sP1/sP2 param tables (3*256 float4 = 12 KB). */
    __shared__ __align__(16) float lds[BLK * H];
    float4* lds4 = (float4*)lds;

    const int tid = threadIdx.x;
    const int b   = blockIdx.x * BLK + tid;

    /* ---- input: 8 features, two float4 loads ---- */
    const float4* gp = (const float4*)(G + (size_t)b * 8);
    const float4 gA = gp[0], gB = gp[1];
    const float g0 = gA.x, g1 = gA.y, g2 = gA.z, g3 = gA.w;
    const float g4 = gB.x, g5 = gB.y, g6 = gB.z, g7 = gB.w;

    /* ---- layer 1: 8 -> 100, ReLU. 4 outputs at a time -> ds_write_b128 own row. ---- */
#pragma unroll
    for (int j4 = 0; j4 < 25; ++j4) {
        float hv[4];
#pragma unroll
        for (int jj = 0; jj < 4; ++jj) {
            const int j = j4 * 4 + jj;
            const float* wr = W1 + j * 8;              /* uniform -> s_load */
            float s0 = fmaf(g0, wr[0], b1[j]);
            float s1 = g1 * wr[1];
            s0 = fmaf(g2, wr[2], s0);  s1 = fmaf(g3, wr[3], s1);
            s0 = fmaf(g4, wr[4], s0);  s1 = fmaf(g5, wr[5], s1);
            s0 = fmaf(g6, wr[6], s0);  s1 = fmaf(g7, wr[7], s1);
            hv[jj] = fmaxf(s0 + s1, 0.f);
        }
        lds4[tid * 25 + j4] = make_float4(hv[0], hv[1], hv[2], hv[3]);
    }
    /* no __syncthreads needed: each thread reads only its OWN row (same-thread RAW). */

    /* ---- layer 2 (100 -> 100, ReLU) j-tiled by 25, fused with the 3 heads ---- */
    float aw0[4] = {0.f,0.f,0.f,0.f};
    float awp[4] = {0.f,0.f,0.f,0.f};
    float agg[4] = {0.f,0.f,0.f,0.f};

#pragma unroll 1
    for (int jt = 0; jt < H / JT; ++jt) {
        const float* W2t = W2 + jt * JT * H;           /* uniform base */
        float acc[JT];
#pragma unroll
        for (int u = 0; u < JT; ++u) acc[u] = b2[jt * JT + u];

#pragma unroll
        for (int k4 = 0; k4 < 25; ++k4) {
            const float4 hv = lds4[tid * 25 + k4];     /* ds_read_b128, own row */
#pragma unroll
            for (int u = 0; u < JT; ++u) {
                const float* wr = W2t + u * H + k4 * 4;   /* uniform -> s_load */
                acc[u] = fmaf(hv.x, wr[0], acc[u]);
                acc[u] = fmaf(hv.y, wr[1], acc[u]);
                acc[u] = fmaf(hv.z, wr[2], acc[u]);
                acc[u] = fmaf(hv.w, wr[3], acc[u]);
            }
        }
#pragma unroll
        for (int u = 0; u < JT; ++u) {
            const float h2 = fmaxf(acc[u], 0.f);
            const int j = jt * JT + u;
#pragma unroll
            for (int m = 0; m < 4; ++m) {
                aw0[m] = fmaf(h2, Ww0[m * H + j], aw0[m]);
                awp[m] = fmaf(h2, Wwp[m * H + j], awp[m]);
                agg[m] = fmaf(h2, Wg [m * H + j], agg[m]);
            }
        }
    }

    /* ---- derived params -> LDS (alias h1 region; all own-row reads are done,
       but other threads' rows overlap -> barrier on both sides) ---- */
    __syncthreads();
    {
        float p0[4], p1[4], p2[4];
#pragma unroll
        for (int m = 0; m < 4; ++m) {
            const float w0 = fmaxf(aw0[m], 0.f);
            const float wp = fmaxf(awp[m], 0.f);
            const float gg = fmaxf(agg[m], 0.f);
            p0[m] = w0 * w0;
            p1[m] = gg * gg;
            p2[m] = wp * wp * gg;
        }
        lds4[          tid] = make_float4(p0[0], p0[1], p0[2], p0[3]);  /* sP0 */
        lds4[BLK     + tid] = make_float4(p1[0], p1[1], p1[2], p1[3]);  /* sP1 */
        lds4[2 * BLK + tid] = make_float4(p2[0], p2[1], p2[2], p2[3]);  /* sP2 */
    }
    __syncthreads();

    /* ---- spectrum: contiguous 256*300-float region per block, float4 stores.
       4 | 300 so a quad never straddles a batch element. Single rcp. ---- */
    float4* out4 = (float4*)out;
    const int base4 = blockIdx.x * TILE4;

    for (int it = 0; it < TILE4 / BLK; ++it) {      /* 75 iterations */
        const int idx4 = it * BLK + tid;            /* [0, 19200) */
        const int e    = idx4 / 75;                 /* element in tile (0..255) */
        const int k4   = idx4 - e * 75;             /* quad within row (0..74) */

        const float4 P0 = lds4[          e];
        const float4 P1 = lds4[BLK     + e];
        const float4 P2 = lds4[2 * BLK + e];

        const float kb = (float)(k4 << 2);
        float4 r;
        float* rp = (float*)&r;
#pragma unroll
        for (int i = 0; i < 4; ++i) {
            const float w   = 0.5f + (kb + (float)i) * 0.015f;
            const float wsq = w * w;
            const float t0 = P0.x - wsq, t1 = P0.y - wsq,
                        t2 = P0.z - wsq, t3 = P0.w - wsq;
            const float d0 = fmaf(t0, t0, wsq * P1.x);
            const float d1 = fmaf(t1, t1, wsq * P1.y);
            const float d2 = fmaf(t2, t2, wsq * P1.z);
            const float d3 = fmaf(t3, t3, wsq * P1.w);
            const float d01 = d0 * d1, d23 = d2 * d3;
            const float D   = d01 * d23;
            const float n01 = fmaf(P2[1], d0, P2[0] * d1);
            const float n23 = fmaf(P2[3], d2, P2[2] * d3);
            const float N   = fmaf(n01, d23, n23 * d01);
            rp[i] = w * (N * __builtin_amdgcn_rcpf(D));
        }
        out4[base4 + idx4] = r;
    }
}

extern "C" void kernel_launch(void* const* d_in, const int* in_sizes, int n_in,
                              void* d_out, int out_size, void* d_ws, size_t ws_size,
                              hipStream_t stream) {
    const float* G   = (const float*)d_in[0];
    const float* W1  = (const float*)d_in[1];
    const float* b1  = (const float*)d_in[2];
    const float* W2  = (const float*)d_in[3];
    const float* b2  = (const float*)d_in[4];
    const float* Ww0 = (const float*)d_in[5];
    const float* Wwp = (const float*)d_in[6];
    const float* Wg  = (const float*)d_in[7];
    float* out = (float*)d_out;

    dim3 grid(BATCH / BLK);   /* 512 blocks */
    dim3 block(BLK);
    lorentz_fused<<<grid, block, 0, stream>>>(G, W1, b1, W2, b2, Ww0, Wwp, Wg, out);
}

// Round 4
// 90.904 us; speedup vs baseline: 6.8300x; 6.8300x over previous
//
#include <hip/hip_runtime.h>

#define BATCH 131072
#define NS    300
#define H     100
#define BLK   256
#define EPB   128                 /* elements per block (64 quads x 2) */
#define NQ4   (EPB * NS / 4)      /* 9600 float4 outputs per block */

/* 25-fold repetition for named h1 scalars (no alloca, no spill heuristics) */
#define REP25(M) M(0) M(1) M(2) M(3) M(4) M(5) M(6) M(7) M(8) M(9) M(10) M(11) \
  M(12) M(13) M(14) M(15) M(16) M(17) M(18) M(19) M(20) M(21) M(22) M(23) M(24)

__device__ __forceinline__ float qswap1(float x) {   /* quad_perm [1,0,3,2] */
    return __int_as_float(__builtin_amdgcn_mov_dpp(__float_as_int(x), 0xB1, 0xF, 0xF, true));
}
__device__ __forceinline__ float qswap2(float x) {   /* quad_perm [2,3,0,1] */
    return __int_as_float(__builtin_amdgcn_mov_dpp(__float_as_int(x), 0x4E, 0xF, 0xF, true));
}

__global__ __launch_bounds__(BLK, 2)
void lorentz_fused(const float* __restrict__ G,  const float* __restrict__ W1,
                   const float* __restrict__ b1, const float* __restrict__ W2,
                   const float* __restrict__ b2, const float* __restrict__ Ww0,
                   const float* __restrict__ Wwp, const float* __restrict__ Wg,
                   float* __restrict__ out)
{
    /* W2 chunked [j][q][28] (25 used, 3 pad) -> per-(j,q) chunk = 7 aligned float4 */
    __shared__ float4 sW2c4[H * 4 * 7];        /* 44800 B */
    __shared__ float4 sHead4[H * 4];           /*  6400 B: (Ww0,Wwp,Wg,0) per (j,q) */
    __shared__ float4 sP04[EPB], sP14[EPB], sP24[EPB];  /* 6144 B params */
    __shared__ float  sW1[H * 8];              /*  3200 B */
    __shared__ float  sB1[H], sB2[H];          /*   800 B */

    const int tid = threadIdx.x;

    /* ---- stage weights (once per block) ---- */
    {
        float* sW2cF = (float*)sW2c4;
        for (int i = tid; i < H * H; i += BLK) {
            int j = i / 100, k = i - j * 100;
            int q = k / 25, kk = k - q * 25;
            sW2cF[(j * 4 + q) * 28 + kk] = W2[i];
        }
        for (int i = tid; i < H * 8; i += BLK) sW1[i] = W1[i];
        for (int i = tid; i < H; i += BLK) { sB1[i] = b1[i]; sB2[i] = b2[i]; }
        float* sHeadF = (float*)sHead4;
        for (int i = tid; i < H * 4; i += BLK) {
            int j = i >> 2, q = i & 3;
            sHeadF[i * 4 + 0] = Ww0[q * H + j];
            sHeadF[i * 4 + 1] = Wwp[q * H + j];
            sHeadF[i * 4 + 2] = Wg [q * H + j];
            sHeadF[i * 4 + 3] = 0.f;
        }
    }
    __syncthreads();

    const int q  = tid & 3;          /* k-chunk / oscillator owner */
    const int pr = tid >> 2;         /* element pair 0..63 */
    const int e0 = blockIdx.x * EPB + pr * 2;

    /* ---- inputs for both elements ---- */
    const float4* g0p = (const float4*)(G + (size_t)e0 * 8);
    const float4 ga0 = g0p[0], gb0 = g0p[1];
    const float4 ga1 = g0p[2], gb1 = g0p[3];

    /* ---- layer 1: each lane computes h1[q*25 .. q*25+24] for 2 elements ---- */
#define H1DECL(i) float h1a_##i, h1b_##i;
    REP25(H1DECL)
#undef H1DECL
#define L1(i) { const float4* r = (const float4*)&sW1[(q * 25 + (i)) * 8];       \
        const float4 ra = r[0], rb = r[1];                                       \
        const float bb = sB1[q * 25 + (i)];                                      \
        float s0 = fmaf(ga0.x, ra.x, bb);  float s1 = ga0.y * ra.y;              \
        s0 = fmaf(ga0.z, ra.z, s0);  s1 = fmaf(ga0.w, ra.w, s1);                 \
        s0 = fmaf(gb0.x, rb.x, s0);  s1 = fmaf(gb0.y, rb.y, s1);                 \
        s0 = fmaf(gb0.z, rb.z, s0);  s1 = fmaf(gb0.w, rb.w, s1);                 \
        h1a_##i = fmaxf(s0 + s1, 0.f);                                           \
        float t0 = fmaf(ga1.x, ra.x, bb);  float t1 = ga1.y * ra.y;              \
        t0 = fmaf(ga1.z, ra.z, t0);  t1 = fmaf(ga1.w, ra.w, t1);                 \
        t0 = fmaf(gb1.x, rb.x, t0);  t1 = fmaf(gb1.y, rb.y, t1);                 \
        t0 = fmaf(gb1.z, rb.z, t0);  t1 = fmaf(gb1.w, rb.w, t1);                 \
        h1b_##i = fmaxf(t0 + t1, 0.f); }
    REP25(L1)
#undef L1

    /* ---- layer 2 + heads: per j, lane does 25-fma partial dot for 2 elements,
       DPP quad butterfly completes the 100-sum, heads accumulate per-lane osc q. */
    float aw0a = 0.f, awpa = 0.f, agga = 0.f;
    float aw0b = 0.f, awpb = 0.f, aggb = 0.f;

#pragma unroll 2
    for (int j = 0; j < H; ++j) {
        const int cb = (j * 4 + q) * 7;
        const float4 c0 = sW2c4[cb + 0], c1 = sW2c4[cb + 1], c2 = sW2c4[cb + 2],
                     c3 = sW2c4[cb + 3], c4 = sW2c4[cb + 4], c5 = sW2c4[cb + 5],
                     c6 = sW2c4[cb + 6];
        const float4 hv  = sHead4[j * 4 + q];
        const float  b2j = sB2[j];

        float pa = 0.f, pb = 0.f;
#define CH(t, i0, i1, i2, i3)                                                    \
        pa = fmaf(h1a_##i0, c##t.x, pa); pb = fmaf(h1b_##i0, c##t.x, pb);        \
        pa = fmaf(h1a_##i1, c##t.y, pa); pb = fmaf(h1b_##i1, c##t.y, pb);        \
        pa = fmaf(h1a_##i2, c##t.z, pa); pb = fmaf(h1b_##i2, c##t.z, pb);        \
        pa = fmaf(h1a_##i3, c##t.w, pa); pb = fmaf(h1b_##i3, c##t.w, pb);
        CH(0, 0, 1, 2, 3)   CH(1, 4, 5, 6, 7)   CH(2, 8, 9, 10, 11)
        CH(3, 12, 13, 14, 15) CH(4, 16, 17, 18, 19) CH(5, 20, 21, 22, 23)
#undef CH
        pa = fmaf(h1a_24, c6.x, pa); pb = fmaf(h1b_24, c6.x, pb);

        float sa = pa + qswap1(pa); sa += qswap2(sa);
        float sb = pb + qswap1(pb); sb += qswap2(sb);
        const float h2a = fmaxf(sa + b2j, 0.f);
        const float h2b = fmaxf(sb + b2j, 0.f);

        aw0a = fmaf(h2a, hv.x, aw0a); awpa = fmaf(h2a, hv.y, awpa); agga = fmaf(h2a, hv.z, agga);
        aw0b = fmaf(h2b, hv.x, aw0b); awpb = fmaf(h2b, hv.y, awpb); aggb = fmaf(h2b, hv.z, aggb);
    }

    /* ---- derived params -> LDS (lane q owns oscillator q of its 2 elements) ---- */
    {
        float* P0 = (float*)sP04; float* P1 = (float*)sP14; float* P2 = (float*)sP24;
        const float w0a = fmaxf(aw0a, 0.f), wpa = fmaxf(awpa, 0.f), gga = fmaxf(agga, 0.f);
        const float w0b = fmaxf(aw0b, 0.f), wpb = fmaxf(awpb, 0.f), ggb = fmaxf(aggb, 0.f);
        const int ia = (pr * 2) * 4 + q, ib = (pr * 2 + 1) * 4 + q;
        P0[ia] = w0a * w0a;        P0[ib] = w0b * w0b;
        P1[ia] = gga * gga;        P1[ib] = ggb * ggb;
        P2[ia] = wpa * wpa * gga;  P2[ib] = wpb * wpb * ggb;
    }
    __syncthreads();

    /* ---- spectrum: block's contiguous 128*300-float region, float4 stores ---- */
    float4* out4 = (float4*)out;
    const size_t base4 = (size_t)blockIdx.x * NQ4;

    for (int it = 0; it < (NQ4 + BLK - 1) / BLK; ++it) {   /* 38 iters, last half-masked */
        const int idx4 = it * BLK + tid;
        if (idx4 < NQ4) {
            const int e  = idx4 / 75;
            const int k4 = idx4 - e * 75;
            const float4 P0 = sP04[e], P1 = sP14[e], P2 = sP24[e];
            const float kb = (float)(k4 << 2);
            float4 r; float* rp = (float*)&r;
#pragma unroll
            for (int i = 0; i < 4; ++i) {
                const float w   = 0.5f + (kb + (float)i) * 0.015f;
                const float wsq = w * w;
                const float t0 = P0.x - wsq, t1 = P0.y - wsq,
                            t2 = P0.z - wsq, t3 = P0.w - wsq;
                const float d0 = fmaf(t0, t0, wsq * P1.x);
                const float d1 = fmaf(t1, t1, wsq * P1.y);
                const float d2 = fmaf(t2, t2, wsq * P1.z);
                const float d3 = fmaf(t3, t3, wsq * P1.w);
                const float d01 = d0 * d1, d23 = d2 * d3;
                const float D   = d01 * d23;
                const float n01 = fmaf(P2.y, d0, P2.x * d1);
                const float n23 = fmaf(P2.w, d2, P2.z * d3);
                const float N   = fmaf(n01, d23, n23 * d01);
                rp[i] = w * (N * __builtin_amdgcn_rcpf(D));
            }
            out4[base4 + idx4] = r;
        }
    }
}

extern "C" void kernel_launch(void* const* d_in, const int* in_sizes, int n_in,
                              void* d_out, int out_size, void* d_ws, size_t ws_size,
                              hipStream_t stream) {
    const float* G   = (const float*)d_in[0];
    const float* W1  = (const float*)d_in[1];
    const float* b1  = (const float*)d_in[2];
    const float* W2  = (const float*)d_in[3];
    const float* b2  = (const float*)d_in[4];
    const float* Ww0 = (const float*)d_in[5];
    const float* Wwp = (const float*)d_in[6];
    const float* Wg  = (const float*)d_in[7];
    float* out = (float*)d_out;

    dim3 grid(BATCH / EPB);   /* 1024 blocks */
    dim3 block(BLK);
    lorentz_fused<<<grid, block, 0, stream>>>(G, W1, b1, W2, b2, Ww0, Wwp, Wg, out);
}

// Round 6
// 81.738 us; speedup vs baseline: 7.5960x; 1.1121x over previous
//
#include <hip/hip_runtime.h>

#define BATCH 131072
#define NS    300
#define H     100
#define BLK   256
#define EPB   256                 /* elements per block (64 quads x 4) */
#define NQ4   (EPB * NS / 4)      /* 19200 float4 outputs per block; 75*BLK exactly */

#define REP25(M) M(0) M(1) M(2) M(3) M(4) M(5) M(6) M(7) M(8) M(9) M(10) M(11) \
  M(12) M(13) M(14) M(15) M(16) M(17) M(18) M(19) M(20) M(21) M(22) M(23) M(24)

__device__ __forceinline__ float qswap1(float x) {   /* quad_perm [1,0,3,2] */
    return __int_as_float(__builtin_amdgcn_mov_dpp(__float_as_int(x), 0xB1, 0xF, 0xF, true));
}
__device__ __forceinline__ float qswap2(float x) {   /* quad_perm [2,3,0,1] */
    return __int_as_float(__builtin_amdgcn_mov_dpp(__float_as_int(x), 0x4E, 0xF, 0xF, true));
}

__global__ __launch_bounds__(BLK, 2)
void lorentz_fused(const float* __restrict__ G,  const float* __restrict__ W1,
                   const float* __restrict__ b1, const float* __restrict__ W2,
                   const float* __restrict__ b2, const float* __restrict__ Ww0,
                   const float* __restrict__ Wwp, const float* __restrict__ Wg,
                   float* __restrict__ out)
{
    /* W2 chunked [j][q][28] (25 used, 3 pad) -> per-(j,q) chunk = 7 aligned float4 */
    __shared__ float4 sW2c4[H * 4 * 7];        /* 44800 B */
    __shared__ float4 sHead4[H * 4];           /*  6400 B: (Ww0,Wwp,Wg,0) per (j,q) */
    __shared__ float4 sP04[EPB], sP14[EPB], sP24[EPB];  /* 12288 B params */
    __shared__ float  sW1[H * 8];              /*  3200 B */
    __shared__ float  sB1[H], sB2[H];          /*   800 B */

    const int tid = threadIdx.x;

    /* ---- stage weights (once per block) ---- */
    {
        float* sW2cF = (float*)sW2c4;
        for (int i = tid; i < H * H; i += BLK) {
            int j = i / 100, k = i - j * 100;
            int q = k / 25, kk = k - q * 25;
            sW2cF[(j * 4 + q) * 28 + kk] = W2[i];
        }
        for (int i = tid; i < H * 8; i += BLK) sW1[i] = W1[i];
        for (int i = tid; i < H; i += BLK) { sB1[i] = b1[i]; sB2[i] = b2[i]; }
        float* sHeadF = (float*)sHead4;
        for (int i = tid; i < H * 4; i += BLK) {
            int j = i >> 2, q = i & 3;
            sHeadF[i * 4 + 0] = Ww0[q * H + j];
            sHeadF[i * 4 + 1] = Wwp[q * H + j];
            sHeadF[i * 4 + 2] = Wg [q * H + j];
            sHeadF[i * 4 + 3] = 0.f;
        }
    }
    __syncthreads();

    const int q  = tid & 3;          /* k-chunk / oscillator owner */
    const int gi = tid >> 2;         /* element group 0..63 (4 elements each) */
    const int e0 = blockIdx.x * EPB + gi * 4;

    /* ---- inputs for 4 elements ---- */
    const float4* gp = (const float4*)(G + (size_t)e0 * 8);
    const float4 ga0 = gp[0], gb0 = gp[1];
    const float4 ga1 = gp[2], gb1 = gp[3];
    const float4 ga2 = gp[4], gb2 = gp[5];
    const float4 ga3 = gp[6], gb3 = gp[7];

    /* ---- layer 1: lane computes h1[q*25 .. q*25+24] for 4 elements ---- */
#define H1DECL(i) float h1a_##i, h1b_##i, h1c_##i, h1d_##i;
    REP25(H1DECL)
#undef H1DECL
#define L1E(dst, ga, gb)                                                        \
        { float s0 = fmaf(ga.x, ra.x, bb);  float s1 = ga.y * ra.y;             \
          s0 = fmaf(ga.z, ra.z, s0);  s1 = fmaf(ga.w, ra.w, s1);                \
          s0 = fmaf(gb.x, rb.x, s0);  s1 = fmaf(gb.y, rb.y, s1);                \
          s0 = fmaf(gb.z, rb.z, s0);  s1 = fmaf(gb.w, rb.w, s1);                \
          dst = fmaxf(s0 + s1, 0.f); }
#define L1(i) { const float4* r = (const float4*)&sW1[(q * 25 + (i)) * 8];      \
        const float4 ra = r[0], rb = r[1];                                      \
        const float bb = sB1[q * 25 + (i)];                                     \
        L1E(h1a_##i, ga0, gb0)  L1E(h1b_##i, ga1, gb1)                          \
        L1E(h1c_##i, ga2, gb2)  L1E(h1d_##i, ga3, gb3) }
    REP25(L1)
#undef L1

    /* ---- layer 2 + heads: per j, 25-fma partial dot x4 elements,
       DPP quad butterfly completes each 100-sum, heads accumulate osc q. ---- */
    float aw0a = 0.f, awpa = 0.f, agga = 0.f;
    float aw0b = 0.f, awpb = 0.f, aggb = 0.f;
    float aw0c = 0.f, awpc = 0.f, aggc = 0.f;
    float aw0d = 0.f, awpd = 0.f, aggd = 0.f;

#pragma unroll 2
    for (int j = 0; j < H; ++j) {
        const int cb = (j * 4 + q) * 7;
        const float4 c0 = sW2c4[cb + 0], c1 = sW2c4[cb + 1], c2 = sW2c4[cb + 2],
                     c3 = sW2c4[cb + 3], c4 = sW2c4[cb + 4], c5 = sW2c4[cb + 5],
                     c6 = sW2c4[cb + 6];
        const float4 hv  = sHead4[j * 4 + q];
        const float  b2j = sB2[j];

        float pa = 0.f, pb = 0.f, pc = 0.f, pd = 0.f;
#define CH1(w, i)                                                               \
        pa = fmaf(h1a_##i, w, pa); pb = fmaf(h1b_##i, w, pb);                   \
        pc = fmaf(h1c_##i, w, pc); pd = fmaf(h1d_##i, w, pd);
#define CH(t, i0, i1, i2, i3)                                                   \
        CH1(c##t.x, i0) CH1(c##t.y, i1) CH1(c##t.z, i2) CH1(c##t.w, i3)
        CH(0, 0, 1, 2, 3)     CH(1, 4, 5, 6, 7)     CH(2, 8, 9, 10, 11)
        CH(3, 12, 13, 14, 15) CH(4, 16, 17, 18, 19) CH(5, 20, 21, 22, 23)
        CH1(c6.x, 24)
#undef CH
#undef CH1
        float sa = pa + qswap1(pa); sa += qswap2(sa);
        float sb = pb + qswap1(pb); sb += qswap2(sb);
        float sc = pc + qswap1(pc); sc += qswap2(sc);
        float sd = pd + qswap1(pd); sd += qswap2(sd);
        const float h2a = fmaxf(sa + b2j, 0.f);
        const float h2b = fmaxf(sb + b2j, 0.f);
        const float h2c = fmaxf(sc + b2j, 0.f);
        const float h2d = fmaxf(sd + b2j, 0.f);

        aw0a = fmaf(h2a, hv.x, aw0a); awpa = fmaf(h2a, hv.y, awpa); agga = fmaf(h2a, hv.z, agga);
        aw0b = fmaf(h2b, hv.x, aw0b); awpb = fmaf(h2b, hv.y, awpb); aggb = fmaf(h2b, hv.z, aggb);
        aw0c = fmaf(h2c, hv.x, aw0c); awpc = fmaf(h2c, hv.y, awpc); aggc = fmaf(h2c, hv.z, aggc);
        aw0d = fmaf(h2d, hv.x, aw0d); awpd = fmaf(h2d, hv.y, awpd); aggd = fmaf(h2d, hv.z, aggd);
    }

    /* ---- derived params -> LDS (lane q owns oscillator q of its 4 elements) ---- */
    {
        float* P0 = (float*)sP04; float* P1 = (float*)sP14; float* P2 = (float*)sP24;
#define EMIT(aw, ap, ag, e)                                                     \
        { const float w0 = fmaxf(aw, 0.f), wp = fmaxf(ap, 0.f), gg = fmaxf(ag, 0.f); \
          const int ix = (gi * 4 + (e)) * 4 + q;                                \
          P0[ix] = w0 * w0;  P1[ix] = gg * gg;  P2[ix] = wp * wp * gg; }
        EMIT(aw0a, awpa, agga, 0)
        EMIT(aw0b, awpb, aggb, 1)
        EMIT(aw0c, awpc, aggc, 2)
        EMIT(aw0d, awpd, aggd, 3)
#undef EMIT
    }
    __syncthreads();

    /* ---- spectrum: block's contiguous 256*300-float region, float4 stores.
       75 iterations exactly; e = idx4/75 spans <=2 values per wave -> broadcast. */
    float4* out4 = (float4*)out;
    const size_t base4 = (size_t)blockIdx.x * NQ4;

    for (int it = 0; it < NQ4 / BLK; ++it) {        /* 75 iterations */
        const int idx4 = it * BLK + tid;
        const int e  = idx4 / 75;
        const int k4 = idx4 - e * 75;
        const float4 P0 = sP04[e], P1 = sP14[e], P2 = sP24[e];
        const float kb = (float)(k4 << 2);
        float4 r; float* rp = (float*)&r;
#pragma unroll
        for (int i = 0; i < 4; ++i) {
            const float w   = 0.5f + (kb + (float)i) * 0.015f;
            const float wsq = w * w;
            const float t0 = P0.x - wsq, t1 = P0.y - wsq,
                        t2 = P0.z - wsq, t3 = P0.w - wsq;
            const float d0 = fmaf(t0, t0, wsq * P1.x);
            const float d1 = fmaf(t1, t1, wsq * P1.y);
            const float d2 = fmaf(t2, t2, wsq * P1.z);
            const float d3 = fmaf(t3, t3, wsq * P1.w);
            const float d01 = d0 * d1, d23 = d2 * d3;
            const float D   = d01 * d23;
            const float n01 = fmaf(P2.y, d0, P2.x * d1);
            const float n23 = fmaf(P2.w, d2, P2.z * d3);
            const float N   = fmaf(n01, d23, n23 * d01);
            rp[i] = w * (N * __builtin_amdgcn_rcpf(D));
        }
        out4[base4 + idx4] = r;
    }
}

extern "C" void kernel_launch(void* const* d_in, const int* in_sizes, int n_in,
                              void* d_out, int out_size, void* d_ws, size_t ws_size,
                              hipStream_t stream) {
    const float* G   = (const float*)d_in[0];
    const float* W1  = (const float*)d_in[1];
    const float* b1  = (const float*)d_in[2];
    const float* W2  = (const float*)d_in[3];
    const float* b2  = (const float*)d_in[4];
    const float* Ww0 = (const float*)d_in[5];
    const float* Wwp = (const float*)d_in[6];
    const float* Wg  = (const float*)d_in[7];
    float* out = (float*)d_out;

    dim3 grid(BATCH / EPB);   /* 512 blocks */
    dim3 block(BLK);
    lorentz_fused<<<grid, block, 0, stream>>>(G, W1, b1, W2, b2, Ww0, Wwp, Wg, out);
}